// Round 2
// baseline (403.966 us; speedup 1.0000x reference)
//
#include <hip/hip_runtime.h>

#define Bn 4
#define Cn 3
#define Hn 384
#define Wn 384
#define NBOXn 10

// ---------- helpers ----------

__device__ __forceinline__ float zp_load(const float* __restrict__ img, int bc, int h, int w) {
    // zero-padded load within one (b,c) plane
    if ((unsigned)h >= (unsigned)Hn || (unsigned)w >= (unsigned)Wn) return 0.0f;
    return img[((size_t)bc * Hn + h) * Wn + w];
}

__device__ __forceinline__ float sobel9(const float a[3][3]) {
    // cross-correlation with KX/KY (lax.conv does NOT flip kernels)
    float gx = (a[0][2] - a[0][0]) + 2.0f * (a[1][2] - a[1][0]) + (a[2][2] - a[2][0]);
    float gy = (a[0][0] - a[2][0]) + 2.0f * (a[0][1] - a[2][1]) + (a[0][2] - a[2][2]);
    return fabsf(gx) + fabsf(gy);
}

__device__ __forceinline__ float waveSum(float x) {
    #pragma unroll
    for (int off = 32; off > 0; off >>= 1) x += __shfl_down(x, off, 64);
    return x;
}

// ---------- kernel 1: global losses ----------
// ws layout: ws[b*3 + 0]=sum|gen - max(vis,mean)|, [1]=sum|ggrad - max(vgrad,mgrad)|,
//            [2]=sum 0.25*((g-v)^2+(g-ir)^2)
__global__ void global_loss_kernel(const float* __restrict__ vis,
                                   const float* __restrict__ ir,
                                   const float* __restrict__ gen,
                                   const float* __restrict__ th,
                                   float* __restrict__ ws) {
    int idx = blockIdx.x * blockDim.x + threadIdx.x;
    float in_c = 0.0f, grad_c = 0.0f, mse_c = 0.0f;
    int b = 0;
    if (idx < Bn * Cn * Hn * Wn) {
        int w = idx % Wn;
        int t = idx / Wn;
        int h = t % Hn;
        int bc = t / Hn;
        b = bc / Cn;

        float av[3][3], at_[3][3], ag[3][3], am[3][3];
        #pragma unroll
        for (int r = 0; r < 3; r++) {
            #pragma unroll
            for (int cc = 0; cc < 3; cc++) {
                int hh = h - 1 + r, ww = w - 1 + cc;
                av[r][cc]  = zp_load(vis, bc, hh, ww);
                at_[r][cc] = zp_load(th,  bc, hh, ww);
                ag[r][cc]  = zp_load(gen, bc, hh, ww);
                am[r][cc]  = 0.5f * av[r][cc] + 0.5f * at_[r][cc];
            }
        }
        float v = av[1][1], g = ag[1][1];
        float irv = ir[idx];
        float mean = am[1][1];
        float mean_max = fmaxf(v, mean);
        in_c  = fabsf(g - mean_max);
        float dv = g - v, di = g - irv;
        mse_c = 0.25f * (dv * dv + di * di);
        float ygrad = sobel9(av);
        float mgrad = sobel9(am);
        float ggrad = sobel9(ag);
        grad_c = fabsf(ggrad - fmaxf(ygrad, mgrad));
    }

    // block reduce (256 threads = 4 waves); block always within one batch
    __shared__ float red[3][4];
    float s0 = waveSum(in_c), s1 = waveSum(grad_c), s2 = waveSum(mse_c);
    int lane = threadIdx.x & 63, wv = threadIdx.x >> 6;
    if (lane == 0) { red[0][wv] = s0; red[1][wv] = s1; red[2][wv] = s2; }
    __syncthreads();
    if (threadIdx.x == 0) {
        atomicAdd(&ws[b * 3 + 0], red[0][0] + red[0][1] + red[0][2] + red[0][3]);
        atomicAdd(&ws[b * 3 + 1], red[1][0] + red[1][1] + red[1][2] + red[1][3]);
        atomicAdd(&ws[b * 3 + 2], red[2][0] + red[2][1] + red[2][2] + red[2][3]);
    }
}

// ---------- kernel 2: per-box losses ----------
// ws_box layout: ws_box[(b*NBOX+n)*2 + 0]=Lssim numer sum, +1 = L1 numer sum
__global__ void box_loss_kernel(const float* __restrict__ vis,
                                const float* __restrict__ gen,
                                const float* __restrict__ th,
                                const int* __restrict__ label,
                                float* __restrict__ ws_box) {
    int bn = blockIdx.y;       // b*NBOX + n
    int b = bn / NBOXn;
    const int* lab = label + bn * 5;
    int x1 = lab[1], y1 = lab[2], x2 = lab[3], y2 = lab[4];
    if ((x1 | y1 | x2 | y2) == 0) return;      // invalid box
    int bw = x2 - x1, bh = y2 - y1;
    if (bw <= 0 || bh <= 0) return;
    int area = bw * bh;
    int total = area * Cn;

    float lssim = 0.0f, l1 = 0.0f;
    int start = blockIdx.x * blockDim.x + threadIdx.x;
    int step  = gridDim.x * blockDim.x;
    for (int e = start; e < total; e += step) {
        int c   = e / area;
        int rem = e - c * area;
        int r   = rem / bw;
        int col = rem - r * bw;
        int h = y1 + r, w = x1 + col;
        int bc = b * Cn + c;

        float mv[3][3], mt[3][3], mg[3][3], mm[3][3];
        #pragma unroll
        for (int rr = 0; rr < 3; rr++) {
            #pragma unroll
            for (int cc = 0; cc < 3; cc++) {
                int hh = h - 1 + rr, ww = w - 1 + cc;
                // box bounds subsume image bounds (0<=y1, y2<=H, 0<=x1, x2<=W)
                bool in = (hh >= y1) && (hh < y2) && (ww >= x1) && (ww < x2);
                if (in) {
                    size_t o = ((size_t)bc * Hn + hh) * Wn + ww;
                    mv[rr][cc] = vis[o];
                    mt[rr][cc] = th[o];
                    mg[rr][cc] = gen[o];
                } else {
                    mv[rr][cc] = 0.0f; mt[rr][cc] = 0.0f; mg[rr][cc] = 0.0f;
                }
                mm[rr][cc] = 0.3f * mv[rr][cc] + 0.7f * mt[rr][cc];
            }
        }
        float gv = sobel9(mv), gm = sobel9(mm), gg = sobel9(mg);
        lssim += fabsf(gg - fmaxf(gv, gm));
        float vcen = mv[1][1], gcen = mg[1][1], mcen = mm[1][1];
        l1 += fabsf(gcen - fmaxf(vcen, mcen));
    }

    __shared__ float red[2][4];
    float s0 = waveSum(lssim), s1 = waveSum(l1);
    int lane = threadIdx.x & 63, wv = threadIdx.x >> 6;
    if (lane == 0) { red[0][wv] = s0; red[1][wv] = s1; }
    __syncthreads();
    if (threadIdx.x == 0) {
        atomicAdd(&ws_box[bn * 2 + 0], red[0][0] + red[0][1] + red[0][2] + red[0][3]);
        atomicAdd(&ws_box[bn * 2 + 1], red[1][0] + red[1][1] + red[1][2] + red[1][3]);
    }
}

// ---------- kernel 3: finalize ----------
__global__ void finalize_kernel(const float* __restrict__ alpha_p,
                                const float* __restrict__ beta_p,
                                const int* __restrict__ label,
                                const float* __restrict__ ws,
                                float* __restrict__ out) {
    int b = threadIdx.x;
    if (b >= Bn) return;
    float alpha = *alpha_p, beta = *beta_p;
    const float invN = 1.0f / (float)(Cn * Hn * Wn);

    float in_sum = ws[b * 3 + 0], grad_sum = ws[b * 3 + 1], mse_sum = ws[b * 3 + 2];
    float loss_in   = 0.5f * in_sum * invN;
    float loss_grad = grad_sum * invN;
    float loss_mse  = mse_sum * invN;
    float loss_global = alpha * (loss_in + loss_mse) + (1.0f - alpha) * loss_grad;

    const float* wb = ws + 3 * Bn;
    float lssim_sum = 0.0f, l1_sum = 0.0f;
    int exist = 0;
    for (int n = 0; n < NBOXn; n++) {
        const int* lab = label + (b * NBOXn + n) * 5;
        int x1 = lab[1], y1 = lab[2], x2 = lab[3], y2 = lab[4];
        bool valid = (x1 | y1 | x2 | y2) != 0;
        float Ls = 0.0f, L1 = 0.0f;
        if (valid) {
            int bw = x2 - x1, bh = y2 - y1;
            int cnt = (bw > 0 && bh > 0) ? bw * bh : 0;
            float denom = fmaxf((float)(cnt * Cn), 1.0f);
            Ls = wb[(b * NBOXn + n) * 2 + 0] / denom;
            L1 = wb[(b * NBOXn + n) * 2 + 1] / denom;
        }
        if (Ls != 0.0f || L1 != 0.0f) { exist++; }
        lssim_sum += Ls;  // zeros contribute nothing, matches ref sum over all n
        l1_sum += L1;
    }
    float ls = 0.0f, lin = 0.0f, loss_label = 0.0f;
    if (exist > 0) {
        float safe = (float)exist;
        ls = lssim_sum / safe;
        lin = l1_sum / safe;
        loss_label = (1.0f - beta) * ls + beta * lin;
    }
    out[0 * Bn + b] = 0.0f;        // loss_ss
    out[1 * Bn + b] = loss_global;
    out[2 * Bn + b] = loss_label;
    out[3 * Bn + b] = loss_in;
    out[4 * Bn + b] = loss_grad;
    out[5 * Bn + b] = ls;
    out[6 * Bn + b] = lin;
}

// ---------- launch ----------
extern "C" void kernel_launch(void* const* d_in, const int* in_sizes, int n_in,
                              void* d_out, int out_size, void* d_ws, size_t ws_size,
                              hipStream_t stream) {
    const float* bp    = (const float*)d_in[0];
    const float* cp    = (const float*)d_in[1];
    const float* vis   = (const float*)d_in[2];
    const float* ir    = (const float*)d_in[3];
    const float* gen   = (const float*)d_in[4];
    const int*   label = (const int*)d_in[5];
    const float* th    = (const float*)d_in[6];
    float* out = (float*)d_out;
    float* ws  = (float*)d_ws;

    // zero accumulators: 3*Bn global + 2*Bn*NBOX box
    hipMemsetAsync(ws, 0, (3 * Bn + 2 * Bn * NBOXn) * sizeof(float), stream);

    int total = Bn * Cn * Hn * Wn;                 // 1,769,472 (divisible by 256)
    global_loss_kernel<<<total / 256, 256, 0, stream>>>(vis, ir, gen, th, ws);

    dim3 bgrid(16, Bn * NBOXn);
    box_loss_kernel<<<bgrid, 256, 0, stream>>>(vis, gen, th, label, ws + 3 * Bn);

    finalize_kernel<<<1, 64, 0, stream>>>(bp, cp, label, ws, out);
}

// Round 3
// 222.729 us; speedup vs baseline: 1.8137x; 1.8137x over previous
//
#include <hip/hip_runtime.h>

#define Bn 4
#define Cn 3
#define Hn 384
#define Wn 384
#define NBOXn 10

#define GBLK 864          // global-kernel blocks
#define CHUNK 2048        // pixels per block (256 thr x 8)
#define BPB 216           // blocks per batch = (Cn*Hn*Wn)/CHUNK = 442368/2048
#define BSLICE 16         // box-kernel x-slices

// ---------- helpers ----------

__device__ __forceinline__ float zp_load(const float* __restrict__ img, int bc, int h, int w) {
    if ((unsigned)h >= (unsigned)Hn || (unsigned)w >= (unsigned)Wn) return 0.0f;
    return img[((size_t)bc * Hn + h) * Wn + w];
}

__device__ __forceinline__ float sobel9(const float a[3][3]) {
    // cross-correlation with KX/KY (lax.conv does NOT flip kernels)
    float gx = (a[0][2] - a[0][0]) + 2.0f * (a[1][2] - a[1][0]) + (a[2][2] - a[2][0]);
    float gy = (a[0][0] - a[2][0]) + 2.0f * (a[0][1] - a[2][1]) + (a[0][2] - a[2][2]);
    return fabsf(gx) + fabsf(gy);
}

__device__ __forceinline__ float waveSum(float x) {
    #pragma unroll
    for (int off = 32; off > 0; off >>= 1) x += __shfl_down(x, off, 64);
    return x;
}

// ---------- kernel 1: global losses ----------
// partials: ws[blk*3 + 0]=sum|gen - max(vis,mean)|, [1]=sum|ggrad - max(vgrad,mgrad)|,
//           [2]=sum 0.25*((g-v)^2+(g-ir)^2)   -- NO atomics, per-block slots
__global__ void global_loss_kernel(const float* __restrict__ vis,
                                   const float* __restrict__ ir,
                                   const float* __restrict__ gen,
                                   const float* __restrict__ th,
                                   float* __restrict__ ws) {
    int blk = blockIdx.x;
    int base = blk * CHUNK;
    float in_c = 0.0f, grad_c = 0.0f, mse_c = 0.0f;

    #pragma unroll
    for (int s = 0; s < CHUNK / 256; s++) {
        int idx = base + s * 256 + threadIdx.x;   // always < Bn*Cn*Hn*Wn
        int w = idx % Wn;
        int t = idx / Wn;
        int h = t % Hn;
        int bc = t / Hn;

        float av[3][3], at_[3][3], ag[3][3], am[3][3];
        #pragma unroll
        for (int r = 0; r < 3; r++) {
            #pragma unroll
            for (int cc = 0; cc < 3; cc++) {
                int hh = h - 1 + r, ww = w - 1 + cc;
                av[r][cc]  = zp_load(vis, bc, hh, ww);
                at_[r][cc] = zp_load(th,  bc, hh, ww);
                ag[r][cc]  = zp_load(gen, bc, hh, ww);
                am[r][cc]  = 0.5f * av[r][cc] + 0.5f * at_[r][cc];
            }
        }
        float v = av[1][1], g = ag[1][1];
        float irv = ir[idx];
        float mean = am[1][1];
        in_c  += fabsf(g - fmaxf(v, mean));
        float dv = g - v, di = g - irv;
        mse_c += 0.25f * (dv * dv + di * di);
        float ygrad = sobel9(av);
        float mgrad = sobel9(am);
        float ggrad = sobel9(ag);
        grad_c += fabsf(ggrad - fmaxf(ygrad, mgrad));
    }

    __shared__ float red[3][4];
    float s0 = waveSum(in_c), s1 = waveSum(grad_c), s2 = waveSum(mse_c);
    int lane = threadIdx.x & 63, wv = threadIdx.x >> 6;
    if (lane == 0) { red[0][wv] = s0; red[1][wv] = s1; red[2][wv] = s2; }
    __syncthreads();
    if (threadIdx.x == 0) {
        ws[blk * 3 + 0] = red[0][0] + red[0][1] + red[0][2] + red[0][3];
        ws[blk * 3 + 1] = red[1][0] + red[1][1] + red[1][2] + red[1][3];
        ws[blk * 3 + 2] = red[2][0] + red[2][1] + red[2][2] + red[2][3];
    }
}

// ---------- kernel 2: per-box losses ----------
// partials: wsb[(bn*BSLICE + slice)*2 + {0,1}]  -- always written (zeros if invalid)
__global__ void box_loss_kernel(const float* __restrict__ vis,
                                const float* __restrict__ gen,
                                const float* __restrict__ th,
                                const int* __restrict__ label,
                                float* __restrict__ wsb) {
    int bn = blockIdx.y;       // b*NBOX + n
    int b = bn / NBOXn;
    const int* lab = label + bn * 5;
    int x1 = lab[1], y1 = lab[2], x2 = lab[3], y2 = lab[4];
    bool valid = ((x1 | y1 | x2 | y2) != 0);
    int bw = x2 - x1, bh = y2 - y1;
    if (bw <= 0 || bh <= 0) valid = false;
    int area = valid ? bw * bh : 0;
    int total = area * Cn;

    float lssim = 0.0f, l1 = 0.0f;
    int start = blockIdx.x * blockDim.x + threadIdx.x;
    int step  = gridDim.x * blockDim.x;
    for (int e = start; e < total; e += step) {
        int c   = e / area;
        int rem = e - c * area;
        int r   = rem / bw;
        int col = rem - r * bw;
        int h = y1 + r, w = x1 + col;
        int bc = b * Cn + c;

        float mv[3][3], mg[3][3], mm[3][3];
        #pragma unroll
        for (int rr = 0; rr < 3; rr++) {
            #pragma unroll
            for (int cc = 0; cc < 3; cc++) {
                int hh = h - 1 + rr, ww = w - 1 + cc;
                // box bounds subsume image bounds (0<=y1, y2<=H, 0<=x1, x2<=W)
                bool in = (hh >= y1) && (hh < y2) && (ww >= x1) && (ww < x2);
                float fv = 0.0f, ft = 0.0f, fg = 0.0f;
                if (in) {
                    size_t o = ((size_t)bc * Hn + hh) * Wn + ww;
                    fv = vis[o]; ft = th[o]; fg = gen[o];
                }
                mv[rr][cc] = fv;
                mg[rr][cc] = fg;
                mm[rr][cc] = 0.3f * fv + 0.7f * ft;
            }
        }
        float gv = sobel9(mv), gm = sobel9(mm), gg = sobel9(mg);
        lssim += fabsf(gg - fmaxf(gv, gm));
        l1 += fabsf(mg[1][1] - fmaxf(mv[1][1], mm[1][1]));
    }

    __shared__ float red[2][4];
    float s0 = waveSum(lssim), s1 = waveSum(l1);
    int lane = threadIdx.x & 63, wv = threadIdx.x >> 6;
    if (lane == 0) { red[0][wv] = s0; red[1][wv] = s1; }
    __syncthreads();
    if (threadIdx.x == 0) {
        wsb[(bn * BSLICE + blockIdx.x) * 2 + 0] = red[0][0] + red[0][1] + red[0][2] + red[0][3];
        wsb[(bn * BSLICE + blockIdx.x) * 2 + 1] = red[1][0] + red[1][1] + red[1][2] + red[1][3];
    }
}

// ---------- kernel 3: finalize (reduce partials + output) ----------
__global__ void finalize_kernel(const float* __restrict__ alpha_p,
                                const float* __restrict__ beta_p,
                                const int* __restrict__ label,
                                const float* __restrict__ ws,
                                float* __restrict__ out) {
    __shared__ float red[3][4];
    __shared__ float gsum[Bn][3];
    __shared__ float boxsum[Bn * NBOXn][2];
    int tid = threadIdx.x;

    // phase 1: reduce global partials per batch (BPB=216 <= 256 threads)
    for (int b = 0; b < Bn; b++) {
        float s0 = 0.0f, s1 = 0.0f, s2 = 0.0f;
        if (tid < BPB) {
            const float* p = ws + (size_t)(b * BPB + tid) * 3;
            s0 = p[0]; s1 = p[1]; s2 = p[2];
        }
        s0 = waveSum(s0); s1 = waveSum(s1); s2 = waveSum(s2);
        int lane = tid & 63, wv = tid >> 6;
        if (lane == 0) { red[0][wv] = s0; red[1][wv] = s1; red[2][wv] = s2; }
        __syncthreads();
        if (tid == 0) {
            gsum[b][0] = red[0][0] + red[0][1] + red[0][2] + red[0][3];
            gsum[b][1] = red[1][0] + red[1][1] + red[1][2] + red[1][3];
            gsum[b][2] = red[2][0] + red[2][1] + red[2][2] + red[2][3];
        }
        __syncthreads();
    }

    // phase 2: sum box partials over slices (threads 0..39)
    const float* wsb = ws + GBLK * 3;
    if (tid < Bn * NBOXn) {
        float a = 0.0f, bsum = 0.0f;
        for (int sl = 0; sl < BSLICE; sl++) {
            a    += wsb[(tid * BSLICE + sl) * 2 + 0];
            bsum += wsb[(tid * BSLICE + sl) * 2 + 1];
        }
        boxsum[tid][0] = a;
        boxsum[tid][1] = bsum;
    }
    __syncthreads();

    // phase 3: per-batch final outputs (threads 0..3)
    if (tid < Bn) {
        int b = tid;
        float alpha = *alpha_p, beta = *beta_p;
        const float invN = 1.0f / (float)(Cn * Hn * Wn);

        float loss_in   = 0.5f * gsum[b][0] * invN;
        float loss_grad = gsum[b][1] * invN;
        float loss_mse  = gsum[b][2] * invN;
        float loss_global = alpha * (loss_in + loss_mse) + (1.0f - alpha) * loss_grad;

        float lssim_sum = 0.0f, l1_sum = 0.0f;
        int exist = 0;
        for (int n = 0; n < NBOXn; n++) {
            const int* lab = label + (b * NBOXn + n) * 5;
            int x1 = lab[1], y1 = lab[2], x2 = lab[3], y2 = lab[4];
            bool valid = (x1 | y1 | x2 | y2) != 0;
            float Ls = 0.0f, L1 = 0.0f;
            if (valid) {
                int bw = x2 - x1, bh = y2 - y1;
                int cnt = (bw > 0 && bh > 0) ? bw * bh : 0;
                float denom = fmaxf((float)(cnt * Cn), 1.0f);
                Ls = boxsum[b * NBOXn + n][0] / denom;
                L1 = boxsum[b * NBOXn + n][1] / denom;
            }
            if (Ls != 0.0f || L1 != 0.0f) exist++;
            lssim_sum += Ls;
            l1_sum += L1;
        }
        float ls = 0.0f, lin = 0.0f, loss_label = 0.0f;
        if (exist > 0) {
            float safe = (float)exist;
            ls = lssim_sum / safe;
            lin = l1_sum / safe;
            loss_label = (1.0f - beta) * ls + beta * lin;
        }
        out[0 * Bn + b] = 0.0f;        // loss_ss
        out[1 * Bn + b] = loss_global;
        out[2 * Bn + b] = loss_label;
        out[3 * Bn + b] = loss_in;
        out[4 * Bn + b] = loss_grad;
        out[5 * Bn + b] = ls;
        out[6 * Bn + b] = lin;
    }
}

// ---------- launch ----------
extern "C" void kernel_launch(void* const* d_in, const int* in_sizes, int n_in,
                              void* d_out, int out_size, void* d_ws, size_t ws_size,
                              hipStream_t stream) {
    const float* bp    = (const float*)d_in[0];
    const float* cp    = (const float*)d_in[1];
    const float* vis   = (const float*)d_in[2];
    const float* ir    = (const float*)d_in[3];
    const float* gen   = (const float*)d_in[4];
    const int*   label = (const int*)d_in[5];
    const float* th    = (const float*)d_in[6];
    float* out = (float*)d_out;
    float* ws  = (float*)d_ws;

    // ws usage: GBLK*3 global partials + 40*BSLICE*2 box partials (~13 KB), all
    // unconditionally written -> no memset needed.
    global_loss_kernel<<<GBLK, 256, 0, stream>>>(vis, ir, gen, th, ws);

    dim3 bgrid(BSLICE, Bn * NBOXn);
    box_loss_kernel<<<bgrid, 256, 0, stream>>>(vis, gen, th, label, ws + GBLK * 3);

    finalize_kernel<<<1, 256, 0, stream>>>(bp, cp, label, ws, out);
}

// Round 4
// 116.631 us; speedup vs baseline: 3.4636x; 1.9097x over previous
//
#include <hip/hip_runtime.h>

#define Bn 4
#define Cn 3
#define Hn 384
#define Wn 384
#define NBOXn 10

#define CHUNK 1024                       // pixels per block
#define GBLK  (Bn * Cn * Hn * Wn / CHUNK)  // 1728 blocks
#define BPB   (GBLK / Bn)                // 432 blocks per batch
#define NACC  23                         // 3 global + 10*2 box accumulators
#define WSTRIDE 24

// ---------- helpers ----------

__device__ __forceinline__ float zp_load(const float* __restrict__ img, int bc, int h, int w) {
    if ((unsigned)h >= (unsigned)Hn || (unsigned)w >= (unsigned)Wn) return 0.0f;
    return img[((size_t)bc * Hn + h) * Wn + w];
}

__device__ __forceinline__ void sobel_xy(const float a[3][3], float& gx, float& gy) {
    // cross-correlation with KX/KY (lax.conv does NOT flip kernels)
    gx = (a[0][2] - a[0][0]) + 2.0f * (a[1][2] - a[1][0]) + (a[2][2] - a[2][0]);
    gy = (a[0][0] - a[2][0]) + 2.0f * (a[0][1] - a[2][1]) + (a[0][2] - a[2][2]);
}

__device__ __forceinline__ float waveSum(float x) {
    #pragma unroll
    for (int off = 32; off > 0; off >>= 1) x += __shfl_down(x, off, 64);
    return x;
}

// ---------- kernel 1: fused global + box losses, one pass over the images ----------
// acc layout per block row (WSTRIDE floats):
//   [0] sum|gen - max(vis, 0.5v+0.5t)|   [1] sum|ggrad - max(ygrad, mgrad)|
//   [2] sum 0.25((g-v)^2 + (g-ir)^2)     [3+2n] box-n Lssim numer   [3+2n+1] box-n L1 numer
__global__ void __launch_bounds__(256)
fused_loss_kernel(const float* __restrict__ vis,
                  const float* __restrict__ ir,
                  const float* __restrict__ gen,
                  const float* __restrict__ th,
                  const int* __restrict__ label,
                  float* __restrict__ ws) {
    int blk = blockIdx.x;
    int b = blk / BPB;                    // uniform per block

    // box coords — uniform, land in SGPRs
    int X1[NBOXn], Y1[NBOXn], X2[NBOXn], Y2[NBOXn];
    #pragma unroll
    for (int n = 0; n < NBOXn; n++) {
        const int* lab = label + (b * NBOXn + n) * 5;
        X1[n] = lab[1]; Y1[n] = lab[2]; X2[n] = lab[3]; Y2[n] = lab[4];
    }

    float acc[NACC];
    #pragma unroll
    for (int j = 0; j < NACC; j++) acc[j] = 0.0f;

    int base = blk * CHUNK;
    #pragma unroll 1                      // keep body small: Round-3 full unroll spilled to scratch
    for (int s = 0; s < CHUNK / 256; s++) {
        int idx = base + s * 256 + (int)threadIdx.x;
        int w = idx % Wn;
        int t = idx / Wn;
        int h = t % Hn;
        int bc = t / Hn;

        float av[3][3], at_[3][3], ag[3][3];
        #pragma unroll
        for (int r = 0; r < 3; r++) {
            #pragma unroll
            for (int c = 0; c < 3; c++) {
                int hh = h - 1 + r, wp = w - 1 + c;
                av[r][c]  = zp_load(vis, bc, hh, wp);
                at_[r][c] = zp_load(th,  bc, hh, wp);
                ag[r][c]  = zp_load(gen, bc, hh, wp);
            }
        }
        float v = av[1][1], g = ag[1][1], tc = at_[1][1];
        float irv = ir[idx];

        // sobel is linear: derive all blended gradients from per-image gx/gy
        float gxv, gyv, gxt, gyt, gxg, gyg;
        sobel_xy(av, gxv, gyv);
        sobel_xy(at_, gxt, gyt);
        sobel_xy(ag, gxg, gyg);
        float ygrad = fabsf(gxv) + fabsf(gyv);
        float mgrad = fabsf(0.5f * (gxv + gxt)) + fabsf(0.5f * (gyv + gyt));
        float g7    = fabsf(0.3f * gxv + 0.7f * gxt) + fabsf(0.3f * gyv + 0.7f * gyt);
        float ggrad = fabsf(gxg) + fabsf(gyg);

        float amc  = 0.5f * v + 0.5f * tc;
        float am7c = 0.3f * v + 0.7f * tc;
        acc[0] += fabsf(g - fmaxf(v, amc));
        float dv = g - v, di = g - irv;
        acc[2] += 0.25f * (dv * dv + di * di);
        acc[1] += fabsf(ggrad - fmaxf(ygrad, mgrad));

        float l1c = fabsf(g - fmaxf(v, am7c));   // box L1 center term (center always in-box)

        #pragma unroll
        for (int n = 0; n < NBOXn; n++) {
            bool inb = (w >= X1[n]) & (w < X2[n]) & (h >= Y1[n]) & (h < Y2[n]);
            if (inb) {
                bool interior = (w - 1 >= X1[n]) & (w + 1 < X2[n]) &
                                (h - 1 >= Y1[n]) & (h + 1 < Y2[n]);
                float gvb, gmb, ggb;
                if (interior) {
                    // all 9 neighbors in box: masked == raw
                    gvb = ygrad; gmb = g7; ggb = ggrad;
                } else {
                    // box-border pixel (~3%): rebuild masked windows from registers
                    float mv[3][3], mm[3][3], mg[3][3];
                    #pragma unroll
                    for (int r = 0; r < 3; r++) {
                        #pragma unroll
                        for (int c = 0; c < 3; c++) {
                            int hh = h - 1 + r, wp = w - 1 + c;
                            bool ib = (hh >= Y1[n]) & (hh < Y2[n]) & (wp >= X1[n]) & (wp < X2[n]);
                            float fv = ib ? av[r][c]  : 0.0f;
                            float ft = ib ? at_[r][c] : 0.0f;
                            float fg = ib ? ag[r][c]  : 0.0f;
                            mv[r][c] = fv;
                            mg[r][c] = fg;
                            mm[r][c] = 0.3f * fv + 0.7f * ft;
                        }
                    }
                    float a1, a2;
                    sobel_xy(mv, a1, a2); gvb = fabsf(a1) + fabsf(a2);
                    sobel_xy(mm, a1, a2); gmb = fabsf(a1) + fabsf(a2);
                    sobel_xy(mg, a1, a2); ggb = fabsf(a1) + fabsf(a2);
                }
                acc[3 + 2 * n]     += fabsf(ggb - fmaxf(gvb, gmb));
                acc[3 + 2 * n + 1] += l1c;
            }
        }
    }

    // block reduce all 23 accumulators, write one partial row per block
    __shared__ float red[NACC][4];
    int lane = threadIdx.x & 63, wv = threadIdx.x >> 6;
    #pragma unroll
    for (int j = 0; j < NACC; j++) {
        float sj = waveSum(acc[j]);
        if (lane == 0) red[j][wv] = sj;
    }
    __syncthreads();
    if (threadIdx.x < NACC) {
        int j = threadIdx.x;
        ws[(size_t)blk * WSTRIDE + j] = red[j][0] + red[j][1] + red[j][2] + red[j][3];
    }
}

// ---------- kernel 2: finalize (one block per batch) ----------
__global__ void __launch_bounds__(256)
finalize_kernel(const float* __restrict__ alpha_p,
                const float* __restrict__ beta_p,
                const int* __restrict__ label,
                const float* __restrict__ ws,
                float* __restrict__ out) {
    int b = blockIdx.x;
    float a[NACC];
    #pragma unroll
    for (int j = 0; j < NACC; j++) a[j] = 0.0f;

    for (int r = threadIdx.x; r < BPB; r += 256) {
        const float* p = ws + (size_t)(b * BPB + r) * WSTRIDE;
        #pragma unroll
        for (int j = 0; j < NACC; j++) a[j] += p[j];
    }

    __shared__ float red[NACC][4];
    int lane = threadIdx.x & 63, wv = threadIdx.x >> 6;
    #pragma unroll
    for (int j = 0; j < NACC; j++) {
        float sj = waveSum(a[j]);
        if (lane == 0) red[j][wv] = sj;
    }
    __syncthreads();

    if (threadIdx.x == 0) {
        float alpha = *alpha_p, beta = *beta_p;
        const float invN = 1.0f / (float)(Cn * Hn * Wn);

        float loss_in   = 0.5f * (red[0][0] + red[0][1] + red[0][2] + red[0][3]) * invN;
        float loss_grad = (red[1][0] + red[1][1] + red[1][2] + red[1][3]) * invN;
        float loss_mse  = (red[2][0] + red[2][1] + red[2][2] + red[2][3]) * invN;
        float loss_global = alpha * (loss_in + loss_mse) + (1.0f - alpha) * loss_grad;

        float lssim_sum = 0.0f, l1_sum = 0.0f;
        int exist = 0;
        for (int n = 0; n < NBOXn; n++) {
            const int* lab = label + (b * NBOXn + n) * 5;
            int x1 = lab[1], y1 = lab[2], x2 = lab[3], y2 = lab[4];
            bool valid = (x1 | y1 | x2 | y2) != 0;
            float Ls = 0.0f, L1 = 0.0f;
            if (valid) {
                int bw = x2 - x1, bh = y2 - y1;
                int cnt = (bw > 0 && bh > 0) ? bw * bh : 0;
                float denom = fmaxf((float)(cnt * Cn), 1.0f);
                int j0 = 3 + 2 * n;
                Ls = (red[j0][0] + red[j0][1] + red[j0][2] + red[j0][3]) / denom;
                L1 = (red[j0 + 1][0] + red[j0 + 1][1] + red[j0 + 1][2] + red[j0 + 1][3]) / denom;
            }
            if (Ls != 0.0f || L1 != 0.0f) exist++;
            lssim_sum += Ls;
            l1_sum += L1;
        }
        float ls = 0.0f, lin = 0.0f, loss_label = 0.0f;
        if (exist > 0) {
            float safe = (float)exist;
            ls = lssim_sum / safe;
            lin = l1_sum / safe;
            loss_label = (1.0f - beta) * ls + beta * lin;
        }
        out[0 * Bn + b] = 0.0f;        // loss_ss
        out[1 * Bn + b] = loss_global;
        out[2 * Bn + b] = loss_label;
        out[3 * Bn + b] = loss_in;
        out[4 * Bn + b] = loss_grad;
        out[5 * Bn + b] = ls;
        out[6 * Bn + b] = lin;
    }
}

// ---------- launch ----------
extern "C" void kernel_launch(void* const* d_in, const int* in_sizes, int n_in,
                              void* d_out, int out_size, void* d_ws, size_t ws_size,
                              hipStream_t stream) {
    const float* bp    = (const float*)d_in[0];
    const float* cp    = (const float*)d_in[1];
    const float* vis   = (const float*)d_in[2];
    const float* ir    = (const float*)d_in[3];
    const float* gen   = (const float*)d_in[4];
    const int*   label = (const int*)d_in[5];
    const float* th    = (const float*)d_in[6];
    float* out = (float*)d_out;
    float* ws  = (float*)d_ws;

    // ws usage: GBLK * WSTRIDE floats = 1728*24*4 B = 166 KB, every slot we read is
    // unconditionally written by the fused kernel -> no memset needed.
    fused_loss_kernel<<<GBLK, 256, 0, stream>>>(vis, ir, gen, th, label, ws);
    finalize_kernel<<<Bn, 256, 0, stream>>>(bp, cp, label, ws, out);
}

// Round 6
// 112.647 us; speedup vs baseline: 3.5861x; 1.0354x over previous
//
#include <hip/hip_runtime.h>

#define Bn 4
#define Cn 3
#define Hn 384
#define Wn 384
#define NBOXn 10

#define TW 128                 // tile width
#define TH 16                  // tile height
#define GX (Wn / TW)           // 3
#define GY (Hn / TH)           // 24
#define GZ (Bn * Cn)           // 12
#define GBLK (GX * GY * GZ)    // 864 blocks
#define BPB (GBLK / Bn)        // 216 blocks per batch
#define NACC 23                // 3 global + 10*2 box accumulators
#define WSTRIDE 24
#define LROWS (TH + 2)         // 18 halo rows
#define LSTR 136               // LDS row stride (floats); row covers w0-4 .. w0+131
#define NSEG (LSTR / 4)        // 34 float4 segments per row

// ---------- helpers ----------

__device__ __forceinline__ float waveSum(float x) {
    #pragma unroll
    for (int off = 32; off > 0; off >>= 1) x += __shfl_down(x, off, 64);
    return x;
}

__device__ __forceinline__ void sobel_xy(const float a[3][3], float& gx, float& gy) {
    // cross-correlation with KX/KY (lax.conv does NOT flip kernels)
    gx = (a[0][2] - a[0][0]) + 2.0f * (a[1][2] - a[1][0]) + (a[2][2] - a[2][0]);
    gy = (a[0][0] - a[2][0]) + 2.0f * (a[0][1] - a[2][1]) + (a[0][2] - a[2][2]);
}

// ---------- kernel 1: fused global + box losses, LDS-tiled ----------
// partial row per block (WSTRIDE floats):
//   [0] sum|gen - max(vis, .5v+.5t)|  [1] sum|ggrad - max(ygrad,mgrad)|
//   [2] sum .25((g-v)^2+(g-ir)^2)     [3+2n]/[4+2n] box-n Lssim/L1 numerators
__global__ void __launch_bounds__(256)
fused_loss_kernel(const float* __restrict__ vis,
                  const float* __restrict__ ir,
                  const float* __restrict__ gen,
                  const float* __restrict__ th,
                  const int* __restrict__ label,
                  float* __restrict__ ws) {
    __shared__ float sV[LROWS * LSTR];
    __shared__ float sT[LROWS * LSTR];
    __shared__ float sG[LROWS * LSTR];

    const int tid = threadIdx.x;
    const int w0 = blockIdx.x * TW;
    const int h0 = blockIdx.y * TH;
    const int bc = blockIdx.z;
    const int b  = bc / Cn;

    // ---- stage halos: float4 loads, zero-padded edges ----
    for (int i = tid; i < LROWS * NSEG; i += 256) {
        int row = i / NSEG, seg = i % NSEG;
        int h  = h0 - 1 + row;
        int wf = w0 - 4 + seg * 4;
        float4 fv, ft, fg;
        if ((unsigned)h < (unsigned)Hn && wf >= 0 && wf <= Wn - 4) {
            size_t o = ((size_t)bc * Hn + h) * Wn + wf;
            fv = *(const float4*)(vis + o);
            ft = *(const float4*)(th  + o);
            fg = *(const float4*)(gen + o);
        } else if ((unsigned)h < (unsigned)Hn) {
            float* pv = &fv.x; float* pt = &ft.x; float* pg = &fg.x;
            size_t ro = ((size_t)bc * Hn + h) * Wn;
            #pragma unroll
            for (int j = 0; j < 4; j++) {
                int wj = wf + j;
                bool in = (unsigned)wj < (unsigned)Wn;
                pv[j] = in ? vis[ro + wj] : 0.0f;
                pt[j] = in ? th [ro + wj] : 0.0f;
                pg[j] = in ? gen[ro + wj] : 0.0f;
            }
        } else {
            fv = make_float4(0.f, 0.f, 0.f, 0.f); ft = fv; fg = fv;
        }
        int lo = row * LSTR + seg * 4;
        *(float4*)&sV[lo] = fv;
        *(float4*)&sT[lo] = ft;
        *(float4*)&sG[lo] = fg;
    }

    // ---- box coords (uniform -> SGPRs) + tile-level rejection ----
    int X1[NBOXn], Y1[NBOXn], X2[NBOXn], Y2[NBOXn];
    bool hit[NBOXn];
    #pragma unroll
    for (int n = 0; n < NBOXn; n++) {
        const int* lab = label + (b * NBOXn + n) * 5;
        X1[n] = lab[1]; Y1[n] = lab[2]; X2[n] = lab[3]; Y2[n] = lab[4];
        hit[n] = (X2[n] > w0) & (X1[n] < w0 + TW) & (Y2[n] > h0) & (Y1[n] < h0 + TH);
    }

    float acc[NACC];
    #pragma unroll
    for (int j = 0; j < NACC; j++) acc[j] = 0.0f;

    __syncthreads();

    // ---- compute: each thread owns one column strip (tx) x 8 rows ----
    const int tx  = tid & (TW - 1);
    const int tyg = tid >> 7;            // 0 or 1
    const int ty0 = tyg * (TH / 2);      // first local row
    const int cl  = tx + 3;              // LDS col of window-left (global w-1)
    const int w   = w0 + tx;

    float av[3][3], atb[3][3], ag[3][3];
    #pragma unroll
    for (int r = 0; r < 2; r++) {
        int lo = (ty0 + r) * LSTR + cl;
        av [r][0] = sV[lo]; av [r][1] = sV[lo + 1]; av [r][2] = sV[lo + 2];
        atb[r][0] = sT[lo]; atb[r][1] = sT[lo + 1]; atb[r][2] = sT[lo + 2];
        ag [r][0] = sG[lo]; ag [r][1] = sG[lo + 1]; ag [r][2] = sG[lo + 2];
    }

    #pragma unroll 1                     // rolled: keeps code small, arrays stay SROA'd
    for (int k = 0; k < TH / 2; k++) {
        int lo = (ty0 + k + 2) * LSTR + cl;
        av [2][0] = sV[lo]; av [2][1] = sV[lo + 1]; av [2][2] = sV[lo + 2];
        atb[2][0] = sT[lo]; atb[2][1] = sT[lo + 1]; atb[2][2] = sT[lo + 2];
        ag [2][0] = sG[lo]; ag [2][1] = sG[lo + 1]; ag [2][2] = sG[lo + 2];

        const int h = h0 + ty0 + k;
        float v = av[1][1], g = ag[1][1], tc = atb[1][1];
        float irv = ir[((size_t)bc * Hn + h) * Wn + w];

        // sobel is linear: all blended gradients from per-image gx/gy
        float gxv, gyv, gxt, gyt, gxg, gyg;
        sobel_xy(av, gxv, gyv);
        sobel_xy(atb, gxt, gyt);
        sobel_xy(ag, gxg, gyg);
        float ygrad = fabsf(gxv) + fabsf(gyv);
        float mgrad = fabsf(0.5f * (gxv + gxt)) + fabsf(0.5f * (gyv + gyt));
        float g7    = fabsf(0.3f * gxv + 0.7f * gxt) + fabsf(0.3f * gyv + 0.7f * gyt);
        float ggrad = fabsf(gxg) + fabsf(gyg);

        float amc  = 0.5f * v + 0.5f * tc;
        float am7c = 0.3f * v + 0.7f * tc;
        acc[0] += fabsf(g - fmaxf(v, amc));
        float dv = g - v, di = g - irv;
        acc[2] += 0.25f * (dv * dv + di * di);
        acc[1] += fabsf(ggrad - fmaxf(ygrad, mgrad));

        float l1c = fabsf(g - fmaxf(v, am7c));   // box L1 center term

        #pragma unroll
        for (int n = 0; n < NBOXn; n++) {
            if (hit[n]) {                         // uniform s_cbranch skip
                bool inb = (w >= X1[n]) & (w < X2[n]) & (h >= Y1[n]) & (h < Y2[n]);
                if (inb) {
                    bool interior = (w - 1 >= X1[n]) & (w + 1 < X2[n]) &
                                    (h - 1 >= Y1[n]) & (h + 1 < Y2[n]);
                    float gvb, gmb, ggb;
                    if (interior) {
                        gvb = ygrad; gmb = g7; ggb = ggrad;   // masked == raw
                    } else {
                        // box-border pixel: rebuild masked windows from registers
                        float mv[3][3], mm[3][3], mg[3][3];
                        #pragma unroll
                        for (int r = 0; r < 3; r++) {
                            #pragma unroll
                            for (int c = 0; c < 3; c++) {
                                int hh = h - 1 + r, wp = w - 1 + c;
                                bool ib = (hh >= Y1[n]) & (hh < Y2[n]) &
                                          (wp >= X1[n]) & (wp < X2[n]);
                                float fv = ib ? av [r][c] : 0.0f;
                                float ft = ib ? atb[r][c] : 0.0f;
                                float fg = ib ? ag [r][c] : 0.0f;
                                mv[r][c] = fv;
                                mg[r][c] = fg;
                                mm[r][c] = 0.3f * fv + 0.7f * ft;
                            }
                        }
                        float a1, a2;
                        sobel_xy(mv, a1, a2); gvb = fabsf(a1) + fabsf(a2);
                        sobel_xy(mm, a1, a2); gmb = fabsf(a1) + fabsf(a2);
                        sobel_xy(mg, a1, a2); ggb = fabsf(a1) + fabsf(a2);
                    }
                    acc[3 + 2 * n]     += fabsf(ggb - fmaxf(gvb, gmb));
                    acc[3 + 2 * n + 1] += l1c;
                }
            }
        }

        // roll window down one row
        #pragma unroll
        for (int c = 0; c < 3; c++) {
            av [0][c] = av [1][c]; av [1][c] = av [2][c];
            atb[0][c] = atb[1][c]; atb[1][c] = atb[2][c];
            ag [0][c] = ag [1][c]; ag [1][c] = ag [2][c];
        }
    }

    // ---- block reduce, one partial row per block ----
    __shared__ float red[NACC][4];
    int lane = tid & 63, wv = tid >> 6;
    #pragma unroll
    for (int j = 0; j < NACC; j++) {
        float sj = waveSum(acc[j]);
        if (lane == 0) red[j][wv] = sj;
    }
    __syncthreads();
    if (tid < NACC) {
        int blk = (bc * GY + blockIdx.y) * GX + blockIdx.x;   // z-major: batch-contiguous
        ws[(size_t)blk * WSTRIDE + tid] = red[tid][0] + red[tid][1] + red[tid][2] + red[tid][3];
    }
}

// ---------- kernel 2: finalize (one block per batch) ----------
__global__ void __launch_bounds__(256)
finalize_kernel(const float* __restrict__ alpha_p,
                const float* __restrict__ beta_p,
                const int* __restrict__ label,
                const float* __restrict__ ws,
                float* __restrict__ out) {
    int b = blockIdx.x;
    float a[NACC];
    #pragma unroll
    for (int j = 0; j < NACC; j++) a[j] = 0.0f;

    for (int r = threadIdx.x; r < BPB; r += 256) {
        const float* p = ws + (size_t)(b * BPB + r) * WSTRIDE;
        #pragma unroll
        for (int j = 0; j < NACC; j++) a[j] += p[j];
    }

    __shared__ float red[NACC][4];
    int lane = threadIdx.x & 63, wv = threadIdx.x >> 6;
    #pragma unroll
    for (int j = 0; j < NACC; j++) {
        float sj = waveSum(a[j]);
        if (lane == 0) red[j][wv] = sj;
    }
    __syncthreads();

    if (threadIdx.x == 0) {
        float alpha = *alpha_p, beta = *beta_p;
        const float invN = 1.0f / (float)(Cn * Hn * Wn);

        float loss_in   = 0.5f * (red[0][0] + red[0][1] + red[0][2] + red[0][3]) * invN;
        float loss_grad = (red[1][0] + red[1][1] + red[1][2] + red[1][3]) * invN;
        float loss_mse  = (red[2][0] + red[2][1] + red[2][2] + red[2][3]) * invN;
        float loss_global = alpha * (loss_in + loss_mse) + (1.0f - alpha) * loss_grad;

        float lssim_sum = 0.0f, l1_sum = 0.0f;
        int exist = 0;
        for (int n = 0; n < NBOXn; n++) {
            const int* lab = label + (b * NBOXn + n) * 5;
            int x1 = lab[1], y1 = lab[2], x2 = lab[3], y2 = lab[4];
            bool valid = (x1 | y1 | x2 | y2) != 0;
            float Ls = 0.0f, L1 = 0.0f;
            if (valid) {
                int bw = x2 - x1, bh = y2 - y1;
                int cnt = (bw > 0 && bh > 0) ? bw * bh : 0;
                float denom = fmaxf((float)(cnt * Cn), 1.0f);
                int j0 = 3 + 2 * n;
                Ls = (red[j0][0] + red[j0][1] + red[j0][2] + red[j0][3]) / denom;
                L1 = (red[j0 + 1][0] + red[j0 + 1][1] + red[j0 + 1][2] + red[j0 + 1][3]) / denom;
            }
            if (Ls != 0.0f || L1 != 0.0f) exist++;
            lssim_sum += Ls;
            l1_sum += L1;
        }
        float ls = 0.0f, lin = 0.0f, loss_label = 0.0f;
        if (exist > 0) {
            float safe = (float)exist;
            ls = lssim_sum / safe;
            lin = l1_sum / safe;
            loss_label = (1.0f - beta) * ls + beta * lin;
        }
        out[0 * Bn + b] = 0.0f;        // loss_ss
        out[1 * Bn + b] = loss_global;
        out[2 * Bn + b] = loss_label;
        out[3 * Bn + b] = loss_in;
        out[4 * Bn + b] = loss_grad;
        out[5 * Bn + b] = ls;
        out[6 * Bn + b] = lin;
    }
}

// ---------- launch ----------
extern "C" void kernel_launch(void* const* d_in, const int* in_sizes, int n_in,
                              void* d_out, int out_size, void* d_ws, size_t ws_size,
                              hipStream_t stream) {
    const float* bp    = (const float*)d_in[0];
    const float* cp    = (const float*)d_in[1];
    const float* vis   = (const float*)d_in[2];
    const float* ir    = (const float*)d_in[3];
    const float* gen   = (const float*)d_in[4];
    const int*   label = (const int*)d_in[5];
    const float* th    = (const float*)d_in[6];
    float* out = (float*)d_out;
    float* ws  = (float*)d_ws;

    // ws: GBLK * WSTRIDE floats = 864*24*4 B = 83 KB, every slot read by finalize is
    // unconditionally written by the fused kernel -> no memset needed.
    dim3 grid(GX, GY, GZ);
    fused_loss_kernel<<<grid, 256, 0, stream>>>(vis, ir, gen, th, label, ws);
    finalize_kernel<<<Bn, 256, 0, stream>>>(bp, cp, label, ws, out);
}